// Round 14
// baseline (197.137 us; speedup 1.0000x reference)
//
#include <hip/hip_runtime.h>

#define SQH 0.70710678118654752440f

// native vector types for nontemporal builtins (HIP vec types are classes)
typedef float nf4 __attribute__((ext_vector_type(4)));
typedef float nf2 __attribute__((ext_vector_type(2)));
__device__ __forceinline__ void nt_store4(float4 v, float4* p) {
  __builtin_nontemporal_store(__builtin_bit_cast(nf4, v), (nf4*)p);
}
__device__ __forceinline__ void nt_store2(float a, float b, float* p) {
  nf2 v = {a, b};
  __builtin_nontemporal_store(v, (nf2*)p);
}

// ---------------- filter constants (fp32) ----------------
namespace dt {
// level-1 filter symmetric halves: unscaled (for lolo) and x sqrt(1/2) (subbands)
constexpr float H0Oh[3] = {-0.05f, 0.25f, 0.5f};
constexpr float H1Oh[4] = {-3.f/280.f, 15.f/280.f, 73.f/280.f, -170.f/280.f};
constexpr float H0Os[3] = {-0.05f*SQH, 0.25f*SQH, 0.5f*SQH};
constexpr float H1Os[4] = {(-3.f/280.f)*SQH, (15.f/280.f)*SQH,
                           (73.f/280.f)*SQH, (-170.f/280.f)*SQH};
// level-2 qshift filters
constexpr float H0B[10] = {0.03516384f, 0.f, -0.08832942f, 0.23389032f, 0.76027237f,
                           0.5875183f, 0.f, -0.11430184f, 0.f, 0.f};
constexpr float H0A[10] = {0.f, 0.f, -0.11430184f, 0.f, 0.5875183f,
                           0.76027237f, 0.23389032f, -0.08832942f, 0.f, 0.03516384f};
constexpr float H1A[10] = {0.03516384f, 0.f, -0.08832942f, -0.23389032f, 0.76027237f,
                           -0.5875183f, 0.f, 0.11430184f, 0.f, 0.f};
constexpr float H1B[10] = {0.f, 0.f, 0.11430184f, 0.f, -0.5875183f,
                           0.76027237f, -0.23389032f, -0.08832942f, 0.f, 0.03516384f};
}

// symmetric reflection for n=512 (single reflection; max overhang here is 10)
__device__ __forceinline__ int refl512(int i) {
  i = (i < 0) ? (-1 - i) : i;
  return (i > 511) ? (1023 - i) : i;
}

// fp16 helpers
__device__ __forceinline__ unsigned int packh2(float a, float b) {
  const unsigned short ua = __builtin_bit_cast(unsigned short, (_Float16)a);
  const unsigned short ub = __builtin_bit_cast(unsigned short, (_Float16)b);
  return (unsigned int)ua | ((unsigned int)ub << 16);
}
__device__ __forceinline__ unsigned short f2h(float a) {
  return __builtin_bit_cast(unsigned short, (_Float16)a);
}
__device__ __forceinline__ float h2f(unsigned short u) {
  return (float)__builtin_bit_cast(_Float16, u);
}
__device__ __forceinline__ float4 h4tof4(ushort4 v) {
  return make_float4(h2f(v.x), h2f(v.y), h2f(v.z), h2f(v.w));
}
__device__ __forceinline__ float2 u2f2(unsigned int u) {
  return make_float2(h2f((unsigned short)(u & 0xffff)),
                     h2f((unsigned short)(u >> 16)));
}

// =====================================================================
// Kernel 1: level-1. NEW: q2c results stored DIRECTLY to outh0 as two
// contiguous 6-float runs per thread (3x nt float2 each) — s_pack LDS
// round-trip deleted. LDS = planes only, 15.7 KB. 3 barriers.
// XCD-contiguous tile swizzle; lolo fp16 planar.
// grid = (16,16,16), 384 threads.
// =====================================================================
__global__ __launch_bounds__(384)
void k_level1(const float* __restrict__ x, unsigned short* __restrict__ lolo,
              float* __restrict__ outh0) {
  // XCD swizzle: flat 0..4095, xcd = flat%8 gets contiguous 512-tile band
  const int flat = blockIdx.x + (blockIdx.y << 4) + (blockIdx.z << 8);
  const int tile = ((flat & 7) << 9) + (flat >> 3);
  const int b  = tile >> 8;
  const int h0 = ((tile >> 4) & 15) << 5;
  const int w0 = (tile & 15) << 5;
  const int t  = threadIdx.x;

  __shared__ float s_lo[3 * 656];    // [c]: 16 rows x 40 + 16 pad
  __shared__ float s_hi[3 * 656];

  const int q = t & 127;             // column id, < 114 active
  const int g = t >> 7;              // 0,1 active (8 rows each); 2 idle
  const bool hact = (q < 114) && (g < 2);
  const float* xc = nullptr;
  int pbase = 0;
  {
    int cw = q / 3, cch = q - 3 * (q / 3);
    if (q >= 114) { cw = 37; cch = 0; }
    xc = x + (size_t)b * 786432 + refl512(w0 - 3 + cw) * 3 + cch;
    pbase = cch * 656 + (8 * (g & 1)) * 40 + cw;
  }

  auto hload = [&](int h, float* v) {
    if (!hact) return;
    const int rb = h0 + 16 * h + 8 * g - 3;
#pragma unroll
    for (int rr = 0; rr < 14; ++rr)
      v[rr] = xc[(size_t)refl512(rb + rr) * 1536];
  };
  auto hfilt = [&](const float* v) {
    if (!hact) return;
    float* plo = s_lo + pbase;
    float* phi = s_hi + pbase;
#pragma unroll
    for (int rr = 0; rr < 8; ++rr) {
      plo[rr*40] = dt::H0Oh[0]*(v[rr+1]+v[rr+5]) + dt::H0Oh[1]*(v[rr+2]+v[rr+4])
                 + dt::H0Oh[2]*v[rr+3];
      phi[rr*40] = dt::H1Oh[0]*(v[rr]+v[rr+6]) + dt::H1Oh[1]*(v[rr+1]+v[rr+5])
                 + dt::H1Oh[2]*(v[rr+2]+v[rr+4]) + dt::H1Oh[3]*v[rr+3];
    }
  };

  const int c   = t % 3;
  const int jq  = (t / 3) & 15;
  const int rp0 = t / 48;                 // 0..7
  const int lobase = c * 656 + 2 * jq;

  // quad phase for half h: computes hl/hh/lh, stores its 12 outh0
  // components directly (comps c*6+0..5 and 18+c*6+0..5), returns ll.
  auto quadphase = [&](int h) -> float4 {
    const int r0 = rp0 << 1;
    float G0[10], G1[10];
    {
      const float2* d = (const float2*)(s_hi + lobase + r0 * 40);
      const float2* e = (const float2*)(s_hi + lobase + r0 * 40 + 40);
#pragma unroll
      for (int u = 0; u < 5; ++u) {
        float2 vd = d[u]; G0[2*u] = vd.x; G0[2*u+1] = vd.y;
        float2 ve = e[u]; G1[2*u] = ve.x; G1[2*u+1] = ve.y;
      }
    }
    const float hl00 = dt::H0Os[0]*(G0[1]+G0[5]) + dt::H0Os[1]*(G0[2]+G0[4]) + dt::H0Os[2]*G0[3];
    const float hl01 = dt::H0Os[0]*(G0[2]+G0[6]) + dt::H0Os[1]*(G0[3]+G0[5]) + dt::H0Os[2]*G0[4];
    const float hl10 = dt::H0Os[0]*(G1[1]+G1[5]) + dt::H0Os[1]*(G1[2]+G1[4]) + dt::H0Os[2]*G1[3];
    const float hl11 = dt::H0Os[0]*(G1[2]+G1[6]) + dt::H0Os[1]*(G1[3]+G1[5]) + dt::H0Os[2]*G1[4];
    const float hh00 = dt::H1Os[0]*(G0[0]+G0[6]) + dt::H1Os[1]*(G0[1]+G0[5]) + dt::H1Os[2]*(G0[2]+G0[4]) + dt::H1Os[3]*G0[3];
    const float hh01 = dt::H1Os[0]*(G0[1]+G0[7]) + dt::H1Os[1]*(G0[2]+G0[6]) + dt::H1Os[2]*(G0[3]+G0[5]) + dt::H1Os[3]*G0[4];
    const float hh10 = dt::H1Os[0]*(G1[0]+G1[6]) + dt::H1Os[1]*(G1[1]+G1[5]) + dt::H1Os[2]*(G1[2]+G1[4]) + dt::H1Os[3]*G1[3];
    const float hh11 = dt::H1Os[0]*(G1[1]+G1[7]) + dt::H1Os[1]*(G1[2]+G1[6]) + dt::H1Os[2]*(G1[3]+G1[5]) + dt::H1Os[3]*G1[4];
    float L0[10], L1[10];
    {
      const float2* a  = (const float2*)(s_lo + lobase + r0 * 40);
      const float2* bq = (const float2*)(s_lo + lobase + r0 * 40 + 40);
#pragma unroll
      for (int u = 0; u < 5; ++u) {
        float2 va = a[u];  L0[2*u] = va.x; L0[2*u+1] = va.y;
        float2 vb = bq[u]; L1[2*u] = vb.x; L1[2*u+1] = vb.y;
      }
    }
    const float lh00 = dt::H1Os[0]*(L0[0]+L0[6]) + dt::H1Os[1]*(L0[1]+L0[5]) + dt::H1Os[2]*(L0[2]+L0[4]) + dt::H1Os[3]*L0[3];
    const float lh01 = dt::H1Os[0]*(L0[1]+L0[7]) + dt::H1Os[1]*(L0[2]+L0[6]) + dt::H1Os[2]*(L0[3]+L0[5]) + dt::H1Os[3]*L0[4];
    const float lh10 = dt::H1Os[0]*(L1[0]+L1[6]) + dt::H1Os[1]*(L1[1]+L1[5]) + dt::H1Os[2]*(L1[2]+L1[4]) + dt::H1Os[3]*L1[3];
    const float lh11 = dt::H1Os[0]*(L1[1]+L1[7]) + dt::H1Os[1]*(L1[2]+L1[6]) + dt::H1Os[2]*(L1[3]+L1[5]) + dt::H1Os[3]*L1[4];

    // direct outh0 stores: gi = h0/2 + 8h + rp0, gj = w0/2 + jq
    {
      const int gi = (h0 >> 1) + (h << 3) + rp0;
      float* ob = outh0 + (((size_t)(b << 8) + gi) * 256 + (w0 >> 1) + jq) * 36
                  + c * 6;
      // re run: bands 0..5
      nt_store2(hl00 - hl11, hh00 - hh11, ob);
      nt_store2(lh00 - lh11, lh00 + lh11, ob + 2);
      nt_store2(hh00 + hh11, hl00 + hl11, ob + 4);
      // im run: bands 0..5 at +18
      nt_store2(hl01 + hl10, hh01 + hh10, ob + 18);
      nt_store2(lh01 + lh10, lh01 - lh10, ob + 20);
      nt_store2(hh01 - hh10, hl01 - hl10, ob + 22);
    }

    float4 ll;
    ll.x = dt::H0Oh[0]*(L0[1]+L0[5]) + dt::H0Oh[1]*(L0[2]+L0[4]) + dt::H0Oh[2]*L0[3];
    ll.y = dt::H0Oh[0]*(L0[2]+L0[6]) + dt::H0Oh[1]*(L0[3]+L0[5]) + dt::H0Oh[2]*L0[4];
    ll.z = dt::H0Oh[0]*(L1[1]+L1[5]) + dt::H0Oh[1]*(L1[2]+L1[4]) + dt::H0Oh[2]*L1[3];
    ll.w = dt::H0Oh[0]*(L1[2]+L1[6]) + dt::H0Oh[1]*(L1[3]+L1[5]) + dt::H0Oh[2]*L1[4];
    return ll;
  };

  // ---------------- schedule (3 barriers) ----------------
  float v0[14], v1[14];
  hload(0, v0);
  hfilt(v0);
  __syncthreads();                              // B1: half-0 planes ready
  hload(1, v1);                                 // prefetch half-1 x rows
  const float4 llA = quadphase(0);              // reads planes, stores direct
  __syncthreads();                              // B2: plane reads done
  hfilt(v1);                                    // overwrite planes with half 1
  __syncthreads();                              // B3: plane writes visible
  const float4 llB = quadphase(1);
  // lolo stores, fp16 packed pairs (half0 rows 2rp0,2rp0+1; half1 +16)
  {
    unsigned short* lp = lolo + (((size_t)(b * 3 + c) * 512) + (h0 + (rp0 << 1))) * 512
                         + w0 + 2 * jq;
    *(unsigned int*)lp              = packh2(llA.x, llA.y);
    *(unsigned int*)(lp + 512)      = packh2(llA.z, llA.w);
    *(unsigned int*)(lp + 16 * 512) = packh2(llB.x, llB.y);
    *(unsigned int*)(lp + 17 * 512) = packh2(llB.z, llB.w);
  }
}

// =====================================================================
// Kernel 2 (FUSED level-2): UNCHANGED from round 13.
// =====================================================================
#define SM(s, c, r, p) (((((s)*3 + (c))*4 + (r))*2 + (p)) * 266)

__global__ __launch_bounds__(256)
void k_level2(const unsigned short* __restrict__ lolo, float* __restrict__ out0,
              float* __restrict__ outh1) {
  // XCD swizzle: 1024 blocks, xcd gets contiguous 128-block band
  const int flat = blockIdx.x;
  const int bi = ((flat & 7) << 7) + (flat >> 3);
  const int b  = bi >> 6;
  const int jb = bi & 63;
  const int t  = threadIdx.x;
  const int n0 = jb << 1;
  const int m0 = jb << 2;

  __shared__ float s_buf[9216];                 // union: fp16 mid (12768 x u16) | fp32 pack
  unsigned short* s_mid16 = (unsigned short*)s_buf;

  // ---- phase 1 main: 768 tasks = np(2) x cc(3) x g(128), rolling rows ----
  for (int k = 0; k < 3; ++k) {
    const int idx = t + (k << 8);
    const int g  = idx & 127;
    const int cc = (idx >> 7) % 3;
    const int np = idx / 384;
    const int n  = n0 + np;
    const ushort4* sp = (const ushort4*)(lolo + (size_t)(b*3+cc) * 262144) + g;
    float4 E[8], O[8];
    const int EOFF[8] = {-8, -4, -2, 0, 2, 4, 6, 10};
    const int OOFF[8] = {-7, -3, -1, 1, 3, 5, 7, 11};
#pragma unroll
    for (int u = 0; u < 8; ++u) {
      E[u] = h4tof4(sp[(size_t)refl512(4*n + EOFF[u]) * 128]);
      O[u] = h4tof4(sp[(size_t)refl512(4*n + OOFF[u]) * 128]);
    }
#define MAD4(acc, h, v) { acc.x += (h)*v.x; acc.y += (h)*v.y; \
                          acc.z += (h)*v.z; acc.w += (h)*v.w; }
    float4 alo  = make_float4(0.f,0.f,0.f,0.f);   // even m, H0B on E
    MAD4(alo,  dt::H0B[0], E[7]); MAD4(alo,  dt::H0B[2], E[6]);
    MAD4(alo,  dt::H0B[3], E[5]); MAD4(alo,  dt::H0B[4], E[4]);
    MAD4(alo,  dt::H0B[5], E[3]); MAD4(alo,  dt::H0B[7], E[1]);
    float4 ahi  = make_float4(0.f,0.f,0.f,0.f);   // even m, H1A on O
    MAD4(ahi,  dt::H1A[0], O[7]); MAD4(ahi,  dt::H1A[2], O[6]);
    MAD4(ahi,  dt::H1A[3], O[5]); MAD4(ahi,  dt::H1A[4], O[4]);
    MAD4(ahi,  dt::H1A[5], O[3]); MAD4(ahi,  dt::H1A[7], O[1]);
    float4 alo2 = make_float4(0.f,0.f,0.f,0.f);   // odd m, H0A on O
    MAD4(alo2, dt::H0A[2], O[6]); MAD4(alo2, dt::H0A[4], O[4]);
    MAD4(alo2, dt::H0A[5], O[3]); MAD4(alo2, dt::H0A[6], O[2]);
    MAD4(alo2, dt::H0A[7], O[1]); MAD4(alo2, dt::H0A[9], O[0]);
    float4 ahi2 = make_float4(0.f,0.f,0.f,0.f);   // odd m, H1B on E
    MAD4(ahi2, dt::H1B[2], E[6]); MAD4(ahi2, dt::H1B[4], E[4]);
    MAD4(ahi2, dt::H1B[5], E[3]); MAD4(ahi2, dt::H1B[6], E[2]);
    MAD4(ahi2, dt::H1B[7], E[1]); MAD4(ahi2, dt::H1B[9], E[0]);
#undef MAD4
    const int me = np << 1, mo = me + 1;
    *(unsigned int*)&s_mid16[SM(0,cc,me,0) + 2*g + 4] = packh2(alo.x,  alo.z);
    *(unsigned int*)&s_mid16[SM(0,cc,me,1) + 2*g + 4] = packh2(alo.y,  alo.w);
    *(unsigned int*)&s_mid16[SM(1,cc,me,0) + 2*g + 4] = packh2(ahi.x,  ahi.z);
    *(unsigned int*)&s_mid16[SM(1,cc,me,1) + 2*g + 4] = packh2(ahi.y,  ahi.w);
    *(unsigned int*)&s_mid16[SM(0,cc,mo,0) + 2*g + 4] = packh2(alo2.x, alo2.z);
    *(unsigned int*)&s_mid16[SM(0,cc,mo,1) + 2*g + 4] = packh2(alo2.y, alo2.w);
    *(unsigned int*)&s_mid16[SM(1,cc,mo,0) + 2*g + 4] = packh2(ahi2.x, ahi2.z);
    *(unsigned int*)&s_mid16[SM(1,cc,mo,1) + 2*g + 4] = packh2(ahi2.y, ahi2.w);
  }

  // ---- phase 1 halo: cols -8..-1, 512..519 (scalar fp16, reflected) ----
  {
    const int mi  = t >> 6;
    const int rem = t & 63;
    if (rem < 48) {
      const int cc = rem >> 4;
      const int hc = rem & 15;
      const int w  = (hc < 8) ? (hc - 8) : (504 + hc);
      const int u  = w >> 1;
      const int par = w & 1;
      const int wc = refl512(w);
      const int n  = n0 + (mi >> 1);
      const unsigned short* sp = lolo + (size_t)(b*3+cc) * 262144 + wc;
      float alo = 0.f, ahi = 0.f;
      if ((mi & 1) == 0) {
#pragma unroll
        for (int q = 0; q < 10; ++q) {
          if (dt::H0B[q] != 0.f) alo += dt::H0B[q] * h2f(sp[(size_t)refl512(4*n+10-2*q)*512]);
          if (dt::H1A[q] != 0.f) ahi += dt::H1A[q] * h2f(sp[(size_t)refl512(4*n+11-2*q)*512]);
        }
      } else {
#pragma unroll
        for (int q = 0; q < 10; ++q) {
          if (dt::H0A[q] != 0.f) alo += dt::H0A[q] * h2f(sp[(size_t)refl512(4*n+11-2*q)*512]);
          if (dt::H1B[q] != 0.f) ahi += dt::H1B[q] * h2f(sp[(size_t)refl512(4*n+10-2*q)*512]);
        }
      }
      s_mid16[SM(0,cc,mi,par) + u + 4] = f2h(alo);
      s_mid16[SM(1,cc,mi,par) + u + 4] = f2h(ahi);
    }
  }
  __syncthreads();

  // ---- phase 2: W-coldfilt + q2c -> regs; out0 stored directly (nt) ----
  float roh[3][12];
#pragma unroll
  for (int k = 0; k < 3; ++k) {
    const int idx = t + (k << 8);
    const int cc = idx % 3;
    const int jj = (idx / 3) & 127;
    const int rp = idx / 384;
    const int base0 = 2 * jj;

    float q_hl[2][2], q_hh[2][2], q_lh[2][2];
#pragma unroll
    for (int r = 0; r < 2; ++r) {
      const int mi = (rp << 1) + r;
      float el[10], ol[10], eh[10], oh[10];
#pragma unroll
      for (int u = 0; u < 5; ++u) {
        const float2 w0v = u2f2(*(const unsigned int*)&s_mid16[SM(0,cc,mi,0) + base0 + 2*u]);
        el[2*u] = w0v.x; el[2*u+1] = w0v.y;
        const float2 w1v = u2f2(*(const unsigned int*)&s_mid16[SM(0,cc,mi,1) + base0 + 2*u]);
        ol[2*u] = w1v.x; ol[2*u+1] = w1v.y;
        const float2 w2v = u2f2(*(const unsigned int*)&s_mid16[SM(1,cc,mi,0) + base0 + 2*u]);
        eh[2*u] = w2v.x; eh[2*u+1] = w2v.y;
        const float2 w3v = u2f2(*(const unsigned int*)&s_mid16[SM(1,cc,mi,1) + base0 + 2*u]);
        oh[2*u] = w3v.x; oh[2*u+1] = w3v.y;
      }
      float ll_e = 0.f, ll_o = 0.f, hl_e = 0.f, hl_o = 0.f;
      float lh_e = 0.f, lh_o = 0.f, hh_e = 0.f, hh_o = 0.f;
#pragma unroll
      for (int q = 0; q < 10; ++q) {       // tap q reads window[9-q]
        if (dt::H0B[q] != 0.f) { ll_e += dt::H0B[q]*el[9-q]; hl_e += dt::H0B[q]*eh[9-q]; }
        if (dt::H0A[q] != 0.f) { ll_o += dt::H0A[q]*ol[9-q]; hl_o += dt::H0A[q]*oh[9-q]; }
        if (dt::H1A[q] != 0.f) { lh_e += dt::H1A[q]*ol[9-q]; hh_e += dt::H1A[q]*oh[9-q]; }
        if (dt::H1B[q] != 0.f) { lh_o += dt::H1B[q]*el[9-q]; hh_o += dt::H1B[q]*eh[9-q]; }
      }
      // lolo2 -> out0 (interleaved [b][h][w][c]), direct nontemporal
      float* o0 = out0 + (((size_t)(b << 8) + (m0 + mi)) * 256 + 2*jj) * 3 + cc;
      __builtin_nontemporal_store(ll_e, o0);
      __builtin_nontemporal_store(ll_o, o0 + 3);
      q_hl[r][0] = hl_e; q_hl[r][1] = hl_o;
      q_hh[r][0] = hh_e; q_hh[r][1] = hh_o;
      q_lh[r][0] = lh_e; q_lh[r][1] = lh_o;
    }
    roh[k][0]  = SQH * (q_hl[0][0] - q_hl[1][1]);   // band0 re
    roh[k][1]  = SQH * (q_hl[0][1] + q_hl[1][0]);   // band0 im
    roh[k][2]  = SQH * (q_hl[0][0] + q_hl[1][1]);   // band5 re
    roh[k][3]  = SQH * (q_hl[0][1] - q_hl[1][0]);   // band5 im
    roh[k][4]  = SQH * (q_hh[0][0] - q_hh[1][1]);   // band1 re
    roh[k][5]  = SQH * (q_hh[0][1] + q_hh[1][0]);   // band1 im
    roh[k][6]  = SQH * (q_hh[0][0] + q_hh[1][1]);   // band4 re
    roh[k][7]  = SQH * (q_hh[0][1] - q_hh[1][0]);   // band4 im
    roh[k][8]  = SQH * (q_lh[0][0] - q_lh[1][1]);   // band2 re
    roh[k][9]  = SQH * (q_lh[0][1] + q_lh[1][0]);   // band2 im
    roh[k][10] = SQH * (q_lh[0][0] + q_lh[1][1]);   // band3 re
    roh[k][11] = SQH * (q_lh[0][1] - q_lh[1][0]);   // band3 im
  }
  __syncthreads();   // all s_mid reads complete -> safe to reuse as fp32 pack

  // ---- pack outh1 into s_buf: [rp][jj][36] (9216 floats exactly) ----
#pragma unroll
  for (int k = 0; k < 3; ++k) {
    const int idx = t + (k << 8);
    const int cc = idx % 3;
    const int jj = (idx / 3) & 127;
    const int rp = idx / 384;
    float* ph = s_buf + rp * 4608 + jj * 36 + cc;   // + comp (comp = ri*18+band*3)
    ph[0]  = roh[k][0];  ph[18] = roh[k][1];
    ph[15] = roh[k][2];  ph[33] = roh[k][3];
    ph[3]  = roh[k][4];  ph[21] = roh[k][5];
    ph[12] = roh[k][6];  ph[30] = roh[k][7];
    ph[6]  = roh[k][8];  ph[24] = roh[k][9];
    ph[9]  = roh[k][10]; ph[27] = roh[k][11];
  }
  __syncthreads();

  // ---- flush outh1: coalesced nontemporal float4 ----
  const float4* sm4 = (const float4*)s_buf;
  float4* d1 = (float4*)(outh1 + (size_t)(b * 128 + 2 * jb) * 4608);
#pragma unroll
  for (int j = 0; j < 9; ++j)
    nt_store4(sm4[t + j * 256], &d1[t + j * 256]);
}

// =====================================================================
extern "C" void kernel_launch(void* const* d_in, const int* in_sizes, int n_in,
                              void* d_out, int out_size, void* d_ws, size_t ws_size,
                              hipStream_t stream) {
  const float* x = (const float*)d_in[0];
  float* out = (float*)d_out;

  float* out0  = out;                    // 16*256*256*3
  float* outh0 = out + 3145728;          // 16*256*256*36
  float* outh1 = out + 40894464;         // 16*128*128*36

  unsigned short* lolo = (unsigned short*)d_ws;  // fp16 planar [b][c][512][512], 24 MB

  k_level1<<<dim3(16, 16, 16), 384, 0, stream>>>(x, lolo, outh0);
  k_level2<<<1024, 256, 0, stream>>>(lolo, out0, outh1);
}

// Round 15
// 60.645 us; speedup vs baseline: 3.2507x; 3.2507x over previous
//
#include <hip/hip_runtime.h>

#define SQH 0.70710678118654752440f

// native vector type for nontemporal builtins (HIP float4 is a class type)
typedef float nf4 __attribute__((ext_vector_type(4)));
__device__ __forceinline__ void nt_store4(float4 v, float4* p) {
  __builtin_nontemporal_store(__builtin_bit_cast(nf4, v), (nf4*)p);
}

// ---------------- filter constants (fp32) ----------------
namespace dt {
// level-1 filter symmetric halves: unscaled (for lolo) and x sqrt(1/2) (subbands)
constexpr float H0Oh[3] = {-0.05f, 0.25f, 0.5f};
constexpr float H1Oh[4] = {-3.f/280.f, 15.f/280.f, 73.f/280.f, -170.f/280.f};
constexpr float H0Os[3] = {-0.05f*SQH, 0.25f*SQH, 0.5f*SQH};
constexpr float H1Os[4] = {(-3.f/280.f)*SQH, (15.f/280.f)*SQH,
                           (73.f/280.f)*SQH, (-170.f/280.f)*SQH};
// level-2 qshift filters
constexpr float H0B[10] = {0.03516384f, 0.f, -0.08832942f, 0.23389032f, 0.76027237f,
                           0.5875183f, 0.f, -0.11430184f, 0.f, 0.f};
constexpr float H0A[10] = {0.f, 0.f, -0.11430184f, 0.f, 0.5875183f,
                           0.76027237f, 0.23389032f, -0.08832942f, 0.f, 0.03516384f};
constexpr float H1A[10] = {0.03516384f, 0.f, -0.08832942f, -0.23389032f, 0.76027237f,
                           -0.5875183f, 0.f, 0.11430184f, 0.f, 0.f};
constexpr float H1B[10] = {0.f, 0.f, 0.11430184f, 0.f, -0.5875183f,
                           0.76027237f, -0.23389032f, -0.08832942f, 0.f, 0.03516384f};
}

// symmetric reflection for n=512 (single reflection; max overhang here is 10)
__device__ __forceinline__ int refl512(int i) {
  i = (i < 0) ? (-1 - i) : i;
  return (i > 511) ? (1023 - i) : i;
}

// fp16 helpers
__device__ __forceinline__ unsigned int packh2(float a, float b) {
  const unsigned short ua = __builtin_bit_cast(unsigned short, (_Float16)a);
  const unsigned short ub = __builtin_bit_cast(unsigned short, (_Float16)b);
  return (unsigned int)ua | ((unsigned int)ub << 16);
}
__device__ __forceinline__ unsigned short f2h(float a) {
  return __builtin_bit_cast(unsigned short, (_Float16)a);
}
__device__ __forceinline__ float h2f(unsigned short u) {
  return (float)__builtin_bit_cast(_Float16, u);
}
__device__ __forceinline__ float4 h4tof4(ushort4 v) {
  return make_float4(h2f(v.x), h2f(v.y), h2f(v.z), h2f(v.w));
}
__device__ __forceinline__ float2 u2f2(unsigned int u) {
  return make_float2(h2f((unsigned short)(u & 0xffff)),
                     h2f((unsigned short)(u >> 16)));
}

// =====================================================================
// Kernel 1: level-1 (R10 structure + XCD-contiguous tile swizzle +
// nontemporal outh0 stores via LDS pack; pack = write-combining stage,
// nt needs lane-consecutive full-line patterns — R14 lesson).
// =====================================================================
__global__ __launch_bounds__(384)
void k_level1(const float* __restrict__ x, unsigned short* __restrict__ lolo,
              float* __restrict__ outh0) {
  // XCD swizzle: flat 0..4095, xcd = flat%8 gets contiguous 512-tile band
  const int flat = blockIdx.x + (blockIdx.y << 4) + (blockIdx.z << 8);
  const int tile = ((flat & 7) << 9) + (flat >> 3);
  const int b  = tile >> 8;
  const int h0 = ((tile >> 4) & 15) << 5;
  const int w0 = (tile & 15) << 5;
  const int t  = threadIdx.x;

  __shared__ float s_lo[3 * 656];    // [c]: 16 rows x 40 + 16 pad
  __shared__ float s_hi[3 * 656];
  __shared__ float s_pack[4608];     // 8 out-rows x 576

  const int q = t & 127;             // column id, < 114 active
  const int g = t >> 7;              // 0,1 active (8 rows each); 2 idle
  const bool hact = (q < 114) && (g < 2);
  const float* xc = nullptr;
  int pbase = 0;
  {
    int cw = q / 3, cch = q - 3 * (q / 3);
    if (q >= 114) { cw = 37; cch = 0; }
    xc = x + (size_t)b * 786432 + refl512(w0 - 3 + cw) * 3 + cch;
    pbase = cch * 656 + (8 * (g & 1)) * 40 + cw;
  }

  auto hload = [&](int h, float* v) {
    if (!hact) return;
    const int rb = h0 + 16 * h + 8 * g - 3;
#pragma unroll
    for (int rr = 0; rr < 14; ++rr)
      v[rr] = xc[(size_t)refl512(rb + rr) * 1536];
  };
  auto hfilt = [&](const float* v) {
    if (!hact) return;
    float* plo = s_lo + pbase;
    float* phi = s_hi + pbase;
#pragma unroll
    for (int rr = 0; rr < 8; ++rr) {
      plo[rr*40] = dt::H0Oh[0]*(v[rr+1]+v[rr+5]) + dt::H0Oh[1]*(v[rr+2]+v[rr+4])
                 + dt::H0Oh[2]*v[rr+3];
      phi[rr*40] = dt::H1Oh[0]*(v[rr]+v[rr+6]) + dt::H1Oh[1]*(v[rr+1]+v[rr+5])
                 + dt::H1Oh[2]*(v[rr+2]+v[rr+4]) + dt::H1Oh[3]*v[rr+3];
    }
  };

  const int c   = t % 3;
  const int jq  = (t / 3) & 15;
  const int rp0 = t / 48;                 // 0..7
  const int lobase = c * 656 + 2 * jq;
  float* pk = s_pack + rp0 * 576 + jq * 36 + c * 6;

  auto quadphase = [&]() -> float4 {
    const int r0 = rp0 << 1;
    float G0[10], G1[10];
    {
      const float2* d = (const float2*)(s_hi + lobase + r0 * 40);
      const float2* e = (const float2*)(s_hi + lobase + r0 * 40 + 40);
#pragma unroll
      for (int u = 0; u < 5; ++u) {
        float2 vd = d[u]; G0[2*u] = vd.x; G0[2*u+1] = vd.y;
        float2 ve = e[u]; G1[2*u] = ve.x; G1[2*u+1] = ve.y;
      }
    }
    const float hl00 = dt::H0Os[0]*(G0[1]+G0[5]) + dt::H0Os[1]*(G0[2]+G0[4]) + dt::H0Os[2]*G0[3];
    const float hl01 = dt::H0Os[0]*(G0[2]+G0[6]) + dt::H0Os[1]*(G0[3]+G0[5]) + dt::H0Os[2]*G0[4];
    const float hl10 = dt::H0Os[0]*(G1[1]+G1[5]) + dt::H0Os[1]*(G1[2]+G1[4]) + dt::H0Os[2]*G1[3];
    const float hl11 = dt::H0Os[0]*(G1[2]+G1[6]) + dt::H0Os[1]*(G1[3]+G1[5]) + dt::H0Os[2]*G1[4];
    const float hh00 = dt::H1Os[0]*(G0[0]+G0[6]) + dt::H1Os[1]*(G0[1]+G0[5]) + dt::H1Os[2]*(G0[2]+G0[4]) + dt::H1Os[3]*G0[3];
    const float hh01 = dt::H1Os[0]*(G0[1]+G0[7]) + dt::H1Os[1]*(G0[2]+G0[6]) + dt::H1Os[2]*(G0[3]+G0[5]) + dt::H1Os[3]*G0[4];
    const float hh10 = dt::H1Os[0]*(G1[0]+G1[6]) + dt::H1Os[1]*(G1[1]+G1[5]) + dt::H1Os[2]*(G1[2]+G1[4]) + dt::H1Os[3]*G1[3];
    const float hh11 = dt::H1Os[0]*(G1[1]+G1[7]) + dt::H1Os[1]*(G1[2]+G1[6]) + dt::H1Os[2]*(G1[3]+G1[5]) + dt::H1Os[3]*G1[4];
    pk[0]  = hl00 - hl11;  pk[18] = hl01 + hl10;   // band 0
    pk[5]  = hl00 + hl11;  pk[23] = hl01 - hl10;   // band 5
    pk[1]  = hh00 - hh11;  pk[19] = hh01 + hh10;   // band 1
    pk[4]  = hh00 + hh11;  pk[22] = hh01 - hh10;   // band 4
    float L0[10], L1[10];
    {
      const float2* a  = (const float2*)(s_lo + lobase + r0 * 40);
      const float2* bq = (const float2*)(s_lo + lobase + r0 * 40 + 40);
#pragma unroll
      for (int u = 0; u < 5; ++u) {
        float2 va = a[u];  L0[2*u] = va.x; L0[2*u+1] = va.y;
        float2 vb = bq[u]; L1[2*u] = vb.x; L1[2*u+1] = vb.y;
      }
    }
    const float lh00 = dt::H1Os[0]*(L0[0]+L0[6]) + dt::H1Os[1]*(L0[1]+L0[5]) + dt::H1Os[2]*(L0[2]+L0[4]) + dt::H1Os[3]*L0[3];
    const float lh01 = dt::H1Os[0]*(L0[1]+L0[7]) + dt::H1Os[1]*(L0[2]+L0[6]) + dt::H1Os[2]*(L0[3]+L0[5]) + dt::H1Os[3]*L0[4];
    const float lh10 = dt::H1Os[0]*(L1[0]+L1[6]) + dt::H1Os[1]*(L1[1]+L1[5]) + dt::H1Os[2]*(L1[2]+L1[4]) + dt::H1Os[3]*L1[3];
    const float lh11 = dt::H1Os[0]*(L1[1]+L1[7]) + dt::H1Os[1]*(L1[2]+L1[6]) + dt::H1Os[2]*(L1[3]+L1[5]) + dt::H1Os[3]*L1[4];
    pk[2]  = lh00 - lh11;  pk[20] = lh01 + lh10;   // band 2
    pk[3]  = lh00 + lh11;  pk[21] = lh01 - lh10;   // band 3
    float4 ll;
    ll.x = dt::H0Oh[0]*(L0[1]+L0[5]) + dt::H0Oh[1]*(L0[2]+L0[4]) + dt::H0Oh[2]*L0[3];
    ll.y = dt::H0Oh[0]*(L0[2]+L0[6]) + dt::H0Oh[1]*(L0[3]+L0[5]) + dt::H0Oh[2]*L0[4];
    ll.z = dt::H0Oh[0]*(L1[1]+L1[5]) + dt::H0Oh[1]*(L1[2]+L1[4]) + dt::H0Oh[2]*L1[3];
    ll.w = dt::H0Oh[0]*(L1[2]+L1[6]) + dt::H0Oh[1]*(L1[3]+L1[5]) + dt::H0Oh[2]*L1[4];
    return ll;
  };

  const float4* sp4 = (const float4*)s_pack;
  auto storePack = [&](int h, float4 f0, float4 f1, float4 f2) {
    const int gi0 = (h0 >> 1) + (h << 3);
    float4* gout = (float4*)(outh0 + ((((size_t)b << 8) + gi0) << 8) * 36
                             + (size_t)(w0 >> 1) * 36);
    { const int it = t;       nt_store4(f0, &gout[(size_t)(it/144) * 2304 + (it%144)]); }
    { const int it = t + 384; nt_store4(f1, &gout[(size_t)(it/144) * 2304 + (it%144)]); }
    { const int it = t + 768; nt_store4(f2, &gout[(size_t)(it/144) * 2304 + (it%144)]); }
  };

  float v0[14], v1[14];
  hload(0, v0);
  hfilt(v0);
  __syncthreads();                              // B1: half-0 planes ready
  hload(1, v1);                                 // prefetch half-1 x rows
  const float4 llA = quadphase();               // half-0 quads -> pack
  __syncthreads();                              // B2: pack ready, plane reads done
  float4 f0 = sp4[t], f1 = sp4[t + 384], f2 = sp4[t + 768];
  hfilt(v1);                                    // overwrite planes with half 1
  __syncthreads();                              // B3: plane writes + pack reads done
  storePack(0, f0, f1, f2);                     // overlaps quad1 compute
  const float4 llB = quadphase();
  __syncthreads();                              // B4: pack ready
  f0 = sp4[t]; f1 = sp4[t + 384]; f2 = sp4[t + 768];
  storePack(1, f0, f1, f2);
  // lolo stores stay NORMAL (re-read by k_level2)
  {
    unsigned short* lp = lolo + (((size_t)(b * 3 + c) * 512) + (h0 + (rp0 << 1))) * 512
                         + w0 + 2 * jq;
    *(unsigned int*)lp              = packh2(llA.x, llA.y);
    *(unsigned int*)(lp + 512)      = packh2(llA.z, llA.w);
    *(unsigned int*)(lp + 16 * 512) = packh2(llB.x, llB.y);
    *(unsigned int*)(lp + 17 * 512) = packh2(llB.z, llB.w);
  }
}

// =====================================================================
// Kernel 2 (FUSED level-2): R11 structure + XCD swizzle + nontemporal
// output stores.
// =====================================================================
#define SM(s, c, r, p) (((((s)*3 + (c))*4 + (r))*2 + (p)) * 266)

__global__ __launch_bounds__(256)
void k_level2(const unsigned short* __restrict__ lolo, float* __restrict__ out0,
              float* __restrict__ outh1) {
  // XCD swizzle: 1024 blocks, xcd gets contiguous 128-block band
  const int flat = blockIdx.x;
  const int bi = ((flat & 7) << 7) + (flat >> 3);
  const int b  = bi >> 6;
  const int jb = bi & 63;
  const int t  = threadIdx.x;
  const int n0 = jb << 1;
  const int m0 = jb << 2;

  __shared__ float s_buf[9216];                 // union: fp16 mid (12768 x u16) | fp32 pack
  unsigned short* s_mid16 = (unsigned short*)s_buf;

  // ---- phase 1 main: 768 tasks = np(2) x cc(3) x g(128), rolling rows ----
  for (int k = 0; k < 3; ++k) {
    const int idx = t + (k << 8);
    const int g  = idx & 127;
    const int cc = (idx >> 7) % 3;
    const int np = idx / 384;
    const int n  = n0 + np;
    const ushort4* sp = (const ushort4*)(lolo + (size_t)(b*3+cc) * 262144) + g;
    float4 E[8], O[8];
    const int EOFF[8] = {-8, -4, -2, 0, 2, 4, 6, 10};
    const int OOFF[8] = {-7, -3, -1, 1, 3, 5, 7, 11};
#pragma unroll
    for (int u = 0; u < 8; ++u) {
      E[u] = h4tof4(sp[(size_t)refl512(4*n + EOFF[u]) * 128]);
      O[u] = h4tof4(sp[(size_t)refl512(4*n + OOFF[u]) * 128]);
    }
#define MAD4(acc, h, v) { acc.x += (h)*v.x; acc.y += (h)*v.y; \
                          acc.z += (h)*v.z; acc.w += (h)*v.w; }
    float4 alo  = make_float4(0.f,0.f,0.f,0.f);   // even m, H0B on E
    MAD4(alo,  dt::H0B[0], E[7]); MAD4(alo,  dt::H0B[2], E[6]);
    MAD4(alo,  dt::H0B[3], E[5]); MAD4(alo,  dt::H0B[4], E[4]);
    MAD4(alo,  dt::H0B[5], E[3]); MAD4(alo,  dt::H0B[7], E[1]);
    float4 ahi  = make_float4(0.f,0.f,0.f,0.f);   // even m, H1A on O
    MAD4(ahi,  dt::H1A[0], O[7]); MAD4(ahi,  dt::H1A[2], O[6]);
    MAD4(ahi,  dt::H1A[3], O[5]); MAD4(ahi,  dt::H1A[4], O[4]);
    MAD4(ahi,  dt::H1A[5], O[3]); MAD4(ahi,  dt::H1A[7], O[1]);
    float4 alo2 = make_float4(0.f,0.f,0.f,0.f);   // odd m, H0A on O
    MAD4(alo2, dt::H0A[2], O[6]); MAD4(alo2, dt::H0A[4], O[4]);
    MAD4(alo2, dt::H0A[5], O[3]); MAD4(alo2, dt::H0A[6], O[2]);
    MAD4(alo2, dt::H0A[7], O[1]); MAD4(alo2, dt::H0A[9], O[0]);
    float4 ahi2 = make_float4(0.f,0.f,0.f,0.f);   // odd m, H1B on E
    MAD4(ahi2, dt::H1B[2], E[6]); MAD4(ahi2, dt::H1B[4], E[4]);
    MAD4(ahi2, dt::H1B[5], E[3]); MAD4(ahi2, dt::H1B[6], E[2]);
    MAD4(ahi2, dt::H1B[7], E[1]); MAD4(ahi2, dt::H1B[9], E[0]);
#undef MAD4
    const int me = np << 1, mo = me + 1;
    *(unsigned int*)&s_mid16[SM(0,cc,me,0) + 2*g + 4] = packh2(alo.x,  alo.z);
    *(unsigned int*)&s_mid16[SM(0,cc,me,1) + 2*g + 4] = packh2(alo.y,  alo.w);
    *(unsigned int*)&s_mid16[SM(1,cc,me,0) + 2*g + 4] = packh2(ahi.x,  ahi.z);
    *(unsigned int*)&s_mid16[SM(1,cc,me,1) + 2*g + 4] = packh2(ahi.y,  ahi.w);
    *(unsigned int*)&s_mid16[SM(0,cc,mo,0) + 2*g + 4] = packh2(alo2.x, alo2.z);
    *(unsigned int*)&s_mid16[SM(0,cc,mo,1) + 2*g + 4] = packh2(alo2.y, alo2.w);
    *(unsigned int*)&s_mid16[SM(1,cc,mo,0) + 2*g + 4] = packh2(ahi2.x, ahi2.z);
    *(unsigned int*)&s_mid16[SM(1,cc,mo,1) + 2*g + 4] = packh2(ahi2.y, ahi2.w);
  }

  // ---- phase 1 halo: cols -8..-1, 512..519 (scalar fp16, reflected) ----
  {
    const int mi  = t >> 6;
    const int rem = t & 63;
    if (rem < 48) {
      const int cc = rem >> 4;
      const int hc = rem & 15;
      const int w  = (hc < 8) ? (hc - 8) : (504 + hc);
      const int u  = w >> 1;
      const int par = w & 1;
      const int wc = refl512(w);
      const int n  = n0 + (mi >> 1);
      const unsigned short* sp = lolo + (size_t)(b*3+cc) * 262144 + wc;
      float alo = 0.f, ahi = 0.f;
      if ((mi & 1) == 0) {
#pragma unroll
        for (int q = 0; q < 10; ++q) {
          if (dt::H0B[q] != 0.f) alo += dt::H0B[q] * h2f(sp[(size_t)refl512(4*n+10-2*q)*512]);
          if (dt::H1A[q] != 0.f) ahi += dt::H1A[q] * h2f(sp[(size_t)refl512(4*n+11-2*q)*512]);
        }
      } else {
#pragma unroll
        for (int q = 0; q < 10; ++q) {
          if (dt::H0A[q] != 0.f) alo += dt::H0A[q] * h2f(sp[(size_t)refl512(4*n+11-2*q)*512]);
          if (dt::H1B[q] != 0.f) ahi += dt::H1B[q] * h2f(sp[(size_t)refl512(4*n+10-2*q)*512]);
        }
      }
      s_mid16[SM(0,cc,mi,par) + u + 4] = f2h(alo);
      s_mid16[SM(1,cc,mi,par) + u + 4] = f2h(ahi);
    }
  }
  __syncthreads();

  // ---- phase 2: W-coldfilt + q2c -> regs; out0 stored directly (nt) ----
  float roh[3][12];
#pragma unroll
  for (int k = 0; k < 3; ++k) {
    const int idx = t + (k << 8);
    const int cc = idx % 3;
    const int jj = (idx / 3) & 127;
    const int rp = idx / 384;
    const int base0 = 2 * jj;

    float q_hl[2][2], q_hh[2][2], q_lh[2][2];
#pragma unroll
    for (int r = 0; r < 2; ++r) {
      const int mi = (rp << 1) + r;
      float el[10], ol[10], eh[10], oh[10];
#pragma unroll
      for (int u = 0; u < 5; ++u) {
        const float2 w0v = u2f2(*(const unsigned int*)&s_mid16[SM(0,cc,mi,0) + base0 + 2*u]);
        el[2*u] = w0v.x; el[2*u+1] = w0v.y;
        const float2 w1v = u2f2(*(const unsigned int*)&s_mid16[SM(0,cc,mi,1) + base0 + 2*u]);
        ol[2*u] = w1v.x; ol[2*u+1] = w1v.y;
        const float2 w2v = u2f2(*(const unsigned int*)&s_mid16[SM(1,cc,mi,0) + base0 + 2*u]);
        eh[2*u] = w2v.x; eh[2*u+1] = w2v.y;
        const float2 w3v = u2f2(*(const unsigned int*)&s_mid16[SM(1,cc,mi,1) + base0 + 2*u]);
        oh[2*u] = w3v.x; oh[2*u+1] = w3v.y;
      }
      float ll_e = 0.f, ll_o = 0.f, hl_e = 0.f, hl_o = 0.f;
      float lh_e = 0.f, lh_o = 0.f, hh_e = 0.f, hh_o = 0.f;
#pragma unroll
      for (int q = 0; q < 10; ++q) {       // tap q reads window[9-q]
        if (dt::H0B[q] != 0.f) { ll_e += dt::H0B[q]*el[9-q]; hl_e += dt::H0B[q]*eh[9-q]; }
        if (dt::H0A[q] != 0.f) { ll_o += dt::H0A[q]*ol[9-q]; hl_o += dt::H0A[q]*oh[9-q]; }
        if (dt::H1A[q] != 0.f) { lh_e += dt::H1A[q]*ol[9-q]; hh_e += dt::H1A[q]*oh[9-q]; }
        if (dt::H1B[q] != 0.f) { lh_o += dt::H1B[q]*el[9-q]; hh_o += dt::H1B[q]*eh[9-q]; }
      }
      // lolo2 -> out0 (interleaved [b][h][w][c]), direct nontemporal
      float* o0 = out0 + (((size_t)(b << 8) + (m0 + mi)) * 256 + 2*jj) * 3 + cc;
      __builtin_nontemporal_store(ll_e, o0);
      __builtin_nontemporal_store(ll_o, o0 + 3);
      q_hl[r][0] = hl_e; q_hl[r][1] = hl_o;
      q_hh[r][0] = hh_e; q_hh[r][1] = hh_o;
      q_lh[r][0] = lh_e; q_lh[r][1] = lh_o;
    }
    roh[k][0]  = SQH * (q_hl[0][0] - q_hl[1][1]);   // band0 re
    roh[k][1]  = SQH * (q_hl[0][1] + q_hl[1][0]);   // band0 im
    roh[k][2]  = SQH * (q_hl[0][0] + q_hl[1][1]);   // band5 re
    roh[k][3]  = SQH * (q_hl[0][1] - q_hl[1][0]);   // band5 im
    roh[k][4]  = SQH * (q_hh[0][0] - q_hh[1][1]);   // band1 re
    roh[k][5]  = SQH * (q_hh[0][1] + q_hh[1][0]);   // band1 im
    roh[k][6]  = SQH * (q_hh[0][0] + q_hh[1][1]);   // band4 re
    roh[k][7]  = SQH * (q_hh[0][1] - q_hh[1][0]);   // band4 im
    roh[k][8]  = SQH * (q_lh[0][0] - q_lh[1][1]);   // band2 re
    roh[k][9]  = SQH * (q_lh[0][1] + q_lh[1][0]);   // band2 im
    roh[k][10] = SQH * (q_lh[0][0] + q_lh[1][1]);   // band3 re
    roh[k][11] = SQH * (q_lh[0][1] - q_lh[1][0]);   // band3 im
  }
  __syncthreads();   // all s_mid reads complete -> safe to reuse as fp32 pack

  // ---- pack outh1 into s_buf: [rp][jj][36] (9216 floats exactly) ----
#pragma unroll
  for (int k = 0; k < 3; ++k) {
    const int idx = t + (k << 8);
    const int cc = idx % 3;
    const int jj = (idx / 3) & 127;
    const int rp = idx / 384;
    float* ph = s_buf + rp * 4608 + jj * 36 + cc;   // + comp (comp = ri*18+band*3)
    ph[0]  = roh[k][0];  ph[18] = roh[k][1];
    ph[15] = roh[k][2];  ph[33] = roh[k][3];
    ph[3]  = roh[k][4];  ph[21] = roh[k][5];
    ph[12] = roh[k][6];  ph[30] = roh[k][7];
    ph[6]  = roh[k][8];  ph[24] = roh[k][9];
    ph[9]  = roh[k][10]; ph[27] = roh[k][11];
  }
  __syncthreads();

  // ---- flush outh1: coalesced nontemporal float4 ----
  const float4* sm4 = (const float4*)s_buf;
  float4* d1 = (float4*)(outh1 + (size_t)(b * 128 + 2 * jb) * 4608);
#pragma unroll
  for (int j = 0; j < 9; ++j)
    nt_store4(sm4[t + j * 256], &d1[t + j * 256]);
}

// =====================================================================
extern "C" void kernel_launch(void* const* d_in, const int* in_sizes, int n_in,
                              void* d_out, int out_size, void* d_ws, size_t ws_size,
                              hipStream_t stream) {
  const float* x = (const float*)d_in[0];
  float* out = (float*)d_out;

  float* out0  = out;                    // 16*256*256*3
  float* outh0 = out + 3145728;          // 16*256*256*36
  float* outh1 = out + 40894464;         // 16*128*128*36

  unsigned short* lolo = (unsigned short*)d_ws;  // fp16 planar [b][c][512][512], 24 MB

  k_level1<<<dim3(16, 16, 16), 384, 0, stream>>>(x, lolo, outh0);
  k_level2<<<1024, 256, 0, stream>>>(lolo, out0, outh1);
}